// Round 2
// baseline (22191.110 us; speedup 1.0000x reference)
//
#include <hip/hip_runtime.h>
#include <math.h>

typedef __attribute__((ext_vector_type(8))) short short8;
typedef __attribute__((ext_vector_type(4))) float floatx4;

#define NB 256      // batch
#define NH 512      // hidden
#define NXP 256     // x' dim
#define NT 512      // timesteps
#define NBLK 256    // persistent grid

__device__ __forceinline__ unsigned short f2bf(float f) {
    union { float f; unsigned u; } x; x.f = f;
    unsigned r = x.u + 0x7FFFu + ((x.u >> 16) & 1u);
    return (unsigned short)(r >> 16);
}
__device__ __forceinline__ float sigmoidf_(float x) { return 1.0f / (1.0f + __expf(-x)); }

__device__ __forceinline__ short8 ld8f32_bf(const float* __restrict__ p) {
    float4 u = *(const float4*)p;
    float4 v = *(const float4*)(p + 4);
    short8 r;
    r[0] = (short)f2bf(u.x); r[1] = (short)f2bf(u.y);
    r[2] = (short)f2bf(u.z); r[3] = (short)f2bf(u.w);
    r[4] = (short)f2bf(v.x); r[5] = (short)f2bf(v.y);
    r[6] = (short)f2bf(v.z); r[7] = (short)f2bf(v.w);
    return r;
}

__global__ void k_cvt(const float* __restrict__ src, unsigned short* __restrict__ dst, int n) {
    int i = blockIdx.x * blockDim.x + threadIdx.x;
    int stride = gridDim.x * blockDim.x;
    for (; i < n; i += stride) dst[i] = f2bf(src[i]);
}

struct KParams {
    const float *xl, *xt, *xw, *xs;
    const float *bih, *bhh, *bt;
    const unsigned short *Wihb, *Whhb, *Wthb, *Wtxb;
    float *hf;
    unsigned short *hbf;
    unsigned short *xpb;
    float *ghb;
    float *out;
    int *barcnt;
};

// Grid barrier: monotonic epoch counter. Relaxed spin (no L2 inv per poll),
// one acquire load on exit. Arrive uses release (wbL2 once).
__device__ __forceinline__ void grid_barrier(int* cnt, int target) {
    __syncthreads();
    if (threadIdx.x == 0) {
        __hip_atomic_fetch_add(cnt, 1, __ATOMIC_RELEASE, __HIP_MEMORY_SCOPE_AGENT);
        while (__hip_atomic_load(cnt, __ATOMIC_RELAXED, __HIP_MEMORY_SCOPE_AGENT) < target) {
            __builtin_amdgcn_s_sleep(1);
        }
        (void)__hip_atomic_load(cnt, __ATOMIC_ACQUIRE, __HIP_MEMORY_SCOPE_AGENT);
    }
    __syncthreads();
}

__global__ __launch_bounds__(256)
void k_persist(KParams P)
{
    const int w    = threadIdx.x >> 6;
    const int lane = threadIdx.x & 63;
    const int lr   = lane & 15;        // A row / B col within fragment
    const int lkrow= lane >> 4;        // 0..3
    const int lk   = lkrow * 8;        // k offset within K=32 slice
    const int gw   = blockIdx.x * 4 + w;

    __shared__ float red[2][3][16][17];

    int bar = 0;

    for (int t = 0; t < NT; ++t) {
        // ================= Phase A: x' (256 tiles) + gh (768 tiles) =================
        if (gw < 256) {
            // x' 16x16 tile, K = 512 (h) + 160 (x)
            const int m0 = (gw >> 4) * 16, n0 = (gw & 15) * 16;
            floatx4 acc = (floatx4){0.f, 0.f, 0.f, 0.f};
            const unsigned short* A  = P.hbf  + (size_t)(m0 + lr) * NH + lk;
            const unsigned short* Bw = P.Wthb + (size_t)(n0 + lr) * NH + lk;
            #pragma unroll
            for (int kb = 0; kb < NH; kb += 32) {
                short8 a = *(const short8*)(A + kb);
                short8 b = *(const short8*)(Bw + kb);
                acc = __builtin_amdgcn_mfma_f32_16x16x32_bf16(a, b, acc, 0, 0, 0);
            }
            const unsigned short* BX = P.Wtxb + (size_t)(n0 + lr) * 160 + lk;
            const size_t r = (size_t)(m0 + lr);
            #pragma unroll
            for (int c = 0; c < 5; ++c) {
                const float* pa = (c < 2) ? P.xl + (r * NT + t) * 64 + c * 32 + lk
                                : (c == 2)? P.xt + (r * NT + t) * 32 + lk
                                : (c == 3)? P.xw + (r * NT + t) * 32 + lk
                                          : P.xs + (r * NT + t) * 32 + lk;
                short8 a = ld8f32_bf(pa);
                short8 b = *(const short8*)(BX + c * 32);
                acc = __builtin_amdgcn_mfma_f32_16x16x32_bf16(a, b, acc, 0, 0, 0);
            }
            const float btv = P.bt[n0 + lr];
            #pragma unroll
            for (int rg = 0; rg < 4; ++rg) {
                int row = m0 + lkrow * 4 + rg;
                P.xpb[(size_t)row * NXP + n0 + lr] = f2bf(tanhf(acc[rg] + btv));
            }
        } else {
            // gh 16x32 tile, K = 512. idx -> gate g, m-tile, j-tile(32)
            const int idx = gw - 256;
            const int g   = idx >> 8;
            const int rem = idx & 255;
            const int m0  = (rem >> 4) * 16;
            const int c0  = g * NH + (rem & 15) * 32;
            floatx4 acc0 = (floatx4){0.f,0.f,0.f,0.f};
            floatx4 acc1 = (floatx4){0.f,0.f,0.f,0.f};
            const unsigned short* A  = P.hbf  + (size_t)(m0 + lr) * NH + lk;
            const unsigned short* B0 = P.Whhb + (size_t)(c0 + lr) * NH + lk;
            const unsigned short* B1 = P.Whhb + (size_t)(c0 + 16 + lr) * NH + lk;
            #pragma unroll
            for (int kb = 0; kb < NH; kb += 32) {
                short8 a  = *(const short8*)(A  + kb);
                short8 b0 = *(const short8*)(B0 + kb);
                short8 b1 = *(const short8*)(B1 + kb);
                acc0 = __builtin_amdgcn_mfma_f32_16x16x32_bf16(a, b0, acc0, 0, 0, 0);
                acc1 = __builtin_amdgcn_mfma_f32_16x16x32_bf16(a, b1, acc1, 0, 0, 0);
            }
            #pragma unroll
            for (int rg = 0; rg < 4; ++rg) {
                int row = m0 + lkrow * 4 + rg;
                P.ghb[(size_t)row * 1536 + c0 + lr]      = acc0[rg];
                P.ghb[(size_t)row * 1536 + c0 + 16 + lr] = acc1[rg];
            }
        }

        ++bar;
        grid_barrier(P.barcnt, NBLK * bar);

        // ================= Phase B: gx (512 tiles, K-split 2) + gate/update ==========
        {
            const int tl    = w >> 1;                     // tile within block: 0/1
            const int khalf = w & 1;
            const int tt    = blockIdx.x * 2 + tl;
            const int b0    = (tt >> 5) * 16;
            const int j0    = (tt & 31) * 16;
            floatx4 ar = (floatx4){0.f,0.f,0.f,0.f};
            floatx4 az = (floatx4){0.f,0.f,0.f,0.f};
            floatx4 an = (floatx4){0.f,0.f,0.f,0.f};
            const int ko = khalf * 128;
            const unsigned short* A  = P.xpb  + (size_t)(b0 + lr) * NXP + ko + lk;
            const unsigned short* Br = P.Wihb + (size_t)(j0 + lr) * NXP + ko + lk;
            const unsigned short* Bz = P.Wihb + (size_t)(512 + j0 + lr) * NXP + ko + lk;
            const unsigned short* Bn = P.Wihb + (size_t)(1024 + j0 + lr) * NXP + ko + lk;
            #pragma unroll
            for (int kb = 0; kb < 128; kb += 32) {
                short8 a  = *(const short8*)(A  + kb);
                short8 br = *(const short8*)(Br + kb);
                short8 bz = *(const short8*)(Bz + kb);
                short8 bn = *(const short8*)(Bn + kb);
                ar = __builtin_amdgcn_mfma_f32_16x16x32_bf16(a, br, ar, 0, 0, 0);
                az = __builtin_amdgcn_mfma_f32_16x16x32_bf16(a, bz, az, 0, 0, 0);
                an = __builtin_amdgcn_mfma_f32_16x16x32_bf16(a, bn, an, 0, 0, 0);
            }
            if (khalf == 1) {
                #pragma unroll
                for (int rg = 0; rg < 4; ++rg) {
                    int row = lkrow * 4 + rg;
                    red[tl][0][row][lr] = ar[rg];
                    red[tl][1][row][lr] = az[rg];
                    red[tl][2][row][lr] = an[rg];
                }
            }
            __syncthreads();
            if (khalf == 0) {
                const int j = j0 + lr;
                const float bi_r = P.bih[j],        bh_r = P.bhh[j];
                const float bi_z = P.bih[512 + j],  bh_z = P.bhh[512 + j];
                const float bi_n = P.bih[1024 + j], bh_n = P.bhh[1024 + j];
                #pragma unroll
                for (int rg = 0; rg < 4; ++rg) {
                    int row = lkrow * 4 + rg;
                    int b   = b0 + row;
                    float gxr = ar[rg] + red[tl][0][row][lr];
                    float gxz = az[rg] + red[tl][1][row][lr];
                    float gxn = an[rg] + red[tl][2][row][lr];
                    float ghr = P.ghb[(size_t)b * 1536 + j];
                    float ghz = P.ghb[(size_t)b * 1536 + 512 + j];
                    float ghn = P.ghb[(size_t)b * 1536 + 1024 + j];
                    float rgate = sigmoidf_(gxr + bi_r + ghr + bh_r);
                    float zgate = sigmoidf_(gxz + bi_z + ghz + bh_z);
                    float ngate = tanhf(gxn + bi_n + rgate * (ghn + bh_n));
                    float hold  = P.hf[(size_t)b * NH + j];
                    float hnew  = (1.0f - zgate) * ngate + zgate * hold;
                    P.hf[(size_t)b * NH + j]  = hnew;
                    P.hbf[(size_t)b * NH + j] = f2bf(hnew);
                    if (t == NT - 1) P.out[(size_t)b * NH + j] = hnew;
                }
            }
        }

        ++bar;
        grid_barrier(P.barcnt, NBLK * bar);
    }
}

extern "C" void kernel_launch(void* const* d_in, const int* in_sizes, int n_in,
                              void* d_out, int out_size, void* d_ws, size_t ws_size,
                              hipStream_t stream)
{
    const float* xl  = (const float*)d_in[0];
    const float* xt_ = (const float*)d_in[1];
    const float* xw  = (const float*)d_in[2];
    const float* xs  = (const float*)d_in[3];
    const float* Wih = (const float*)d_in[4];
    const float* Whh = (const float*)d_in[5];
    const float* bih = (const float*)d_in[6];
    const float* bhh = (const float*)d_in[7];
    const float* Wth = (const float*)d_in[8];
    const float* Wtx = (const float*)d_in[9];
    const float* bt  = (const float*)d_in[10];

    // workspace layout (barrier counter first, own 256B line)
    char* p = (char*)d_ws;
    int* barcnt = (int*)p;                     p += 256;
    float* hf   = (float*)p;                   p += (size_t)NB * NH * 4;
    float* ghb  = (float*)p;                   p += (size_t)NB * 1536 * 4;
    unsigned short* hbf = (unsigned short*)p;  p += (size_t)NB * NH * 2;
    unsigned short* xpb = (unsigned short*)p;  p += (size_t)NB * NXP * 2;
    unsigned short* Wihb = (unsigned short*)p; p += (size_t)1536 * 256 * 2;
    unsigned short* Whhb = (unsigned short*)p; p += (size_t)1536 * 512 * 2;
    unsigned short* Wthb = (unsigned short*)p; p += (size_t)256 * 512 * 2;
    unsigned short* Wtxb = (unsigned short*)p; p += (size_t)256 * 160 * 2;
    if ((size_t)(p - (char*)d_ws) > ws_size) return;  // loud fail via validation

    k_cvt<<<256, 256, 0, stream>>>(Wih, Wihb, 1536 * 256);
    k_cvt<<<256, 256, 0, stream>>>(Whh, Whhb, 1536 * 512);
    k_cvt<<<64, 256, 0, stream>>>(Wth, Wthb, 256 * 512);
    k_cvt<<<32, 256, 0, stream>>>(Wtx, Wtxb, 256 * 160);
    hipMemsetAsync(barcnt, 0, 4, stream);
    hipMemsetAsync(hf, 0, (size_t)NB * NH * 4, stream);
    hipMemsetAsync(hbf, 0, (size_t)NB * NH * 2, stream);

    KParams P;
    P.xl = xl; P.xt = xt_; P.xw = xw; P.xs = xs;
    P.bih = bih; P.bhh = bhh; P.bt = bt;
    P.Wihb = Wihb; P.Whhb = Whhb; P.Wthb = Wthb; P.Wtxb = Wtxb;
    P.hf = hf; P.hbf = hbf; P.xpb = xpb; P.ghb = ghb;
    P.out = (float*)d_out; P.barcnt = barcnt;

    void* args[] = { &P };
    if (hipLaunchCooperativeKernel((const void*)k_persist, dim3(NBLK), dim3(256),
                                   args, 0, stream) != hipSuccess) {
        k_persist<<<NBLK, 256, 0, stream>>>(P);
    }
}

// Round 3
// 7057.662 us; speedup vs baseline: 3.1443x; 3.1443x over previous
//
#include <hip/hip_runtime.h>
#include <math.h>

typedef __attribute__((ext_vector_type(8))) short short8;
typedef __attribute__((ext_vector_type(4))) float floatx4;
typedef __attribute__((ext_vector_type(4))) unsigned uintx4;

#define NB 256
#define NH 512
#define NXP 256
#define NT 512
#define GHP 100   // padded f32 row stride for gh/gx LDS tiles

#define MFMA __builtin_amdgcn_mfma_f32_16x16x32_bf16

__device__ __forceinline__ unsigned short f2bf(float f) {
    union { float f; unsigned u; } x; x.f = f;
    unsigned r = x.u + 0x7FFFu + ((x.u >> 16) & 1u);
    return (unsigned short)(r >> 16);
}
__device__ __forceinline__ float sigmoidf_(float x) { return 1.0f / (1.0f + __expf(-x)); }

__device__ __forceinline__ short8 ld8f32_bf(const float* __restrict__ p) {
    float4 u = *(const float4*)p;
    float4 v = *(const float4*)(p + 4);
    short8 r;
    r[0] = (short)f2bf(u.x); r[1] = (short)f2bf(u.y);
    r[2] = (short)f2bf(u.z); r[3] = (short)f2bf(u.w);
    r[4] = (short)f2bf(v.x); r[5] = (short)f2bf(v.y);
    r[6] = (short)f2bf(v.z); r[7] = (short)f2bf(v.w);
    return r;
}

// ---- device-coherent (L3-level) access: sc0 sc1, no cache-wide maintenance ----
__device__ __forceinline__ void ldg4_coh(const void* p0, const void* p1,
                                         const void* p2, const void* p3,
                                         uintx4& r0, uintx4& r1, uintx4& r2, uintx4& r3) {
    asm volatile(
        "global_load_dwordx4 %0, %4, off sc0 sc1\n\t"
        "global_load_dwordx4 %1, %5, off sc0 sc1\n\t"
        "global_load_dwordx4 %2, %6, off sc0 sc1\n\t"
        "global_load_dwordx4 %3, %7, off sc0 sc1\n\t"
        "s_waitcnt vmcnt(0)"
        : "=&v"(r0), "=&v"(r1), "=&v"(r2), "=&v"(r3)
        : "v"(p0), "v"(p1), "v"(p2), "v"(p3)
        : "memory");
}
__device__ __forceinline__ void ldg2_coh(const void* p0, const void* p1,
                                         uintx4& r0, uintx4& r1) {
    asm volatile(
        "global_load_dwordx4 %0, %2, off sc0 sc1\n\t"
        "global_load_dwordx4 %1, %3, off sc0 sc1\n\t"
        "s_waitcnt vmcnt(0)"
        : "=&v"(r0), "=&v"(r1)
        : "v"(p0), "v"(p1)
        : "memory");
}
__device__ __forceinline__ void stg_short_coh(void* p, unsigned v) {
    asm volatile("global_store_short %0, %1, off sc0 sc1" :: "v"(p), "v"(v) : "memory");
}
__device__ __forceinline__ void vm_drain() {
    asm volatile("s_waitcnt vmcnt(0)" ::: "memory");
}

__global__ void k_cvt(const float* __restrict__ src, unsigned short* __restrict__ dst, int n) {
    int i = blockIdx.x * blockDim.x + threadIdx.x;
    int stride = gridDim.x * blockDim.x;
    for (; i < n; i += stride) dst[i] = f2bf(src[i]);
}

struct KParams {
    const float *xl, *xt, *xw, *xs;
    const float *bih, *bhh, *bt;
    const unsigned short *Wihb, *Whhb, *Wthb, *Wtxb;
    unsigned short *hbf, *xpb;
    float *out;
    int *l1, *root;
};

// Tree barrier, RELAXED atomics only (no implicit cache ops).
// Level 1: 8 counters (256B apart), 32 arrivals each; last arrival bumps root.
__device__ __forceinline__ void gbar(int* l1, int* root, int ep, int bid) {
    __syncthreads();
    if (threadIdx.x == 0) {
        int old = __hip_atomic_fetch_add(l1 + (bid & 7) * 64, 1,
                                         __ATOMIC_RELAXED, __HIP_MEMORY_SCOPE_AGENT);
        if (old == ep * 32 - 1)
            __hip_atomic_fetch_add(root, 1, __ATOMIC_RELAXED, __HIP_MEMORY_SCOPE_AGENT);
        while (__hip_atomic_load(root, __ATOMIC_RELAXED, __HIP_MEMORY_SCOPE_AGENT) < ep * 8)
            __builtin_amdgcn_s_sleep(2);
    }
    __syncthreads();
}

__global__ __launch_bounds__(256)
void k_persist(KParams P)
{
    const int tid  = threadIdx.x;
    const int w    = tid >> 6;
    const int lane = tid & 63;
    const int lr   = lane & 15;
    const int lkrow= lane >> 4;
    const int lk   = lkrow * 8;
    const int bid  = blockIdx.x;
    const int m0   = (bid >> 4) * 16;   // batch rows m0..m0+15
    const int jc   = bid & 15;
    const int n0   = jc * 16;           // x' cols n0..n0+15
    const int j0   = jc * 32;           // h cols j0..j0+31 (gate slice)

    __shared__ unsigned short sh_h[16 * 512];   // h rows, bf16, XOR-swizzled
    __shared__ unsigned short sh_xp[16 * 256];  // x' rows, bf16, XOR-swizzled
    __shared__ float sh_gh[16 * GHP];           // gh slice (r|z|n x 32)
    __shared__ float sh_gx[2][16 * GHP];        // gx K-halves
    __shared__ float sh_hf[16 * 32];            // persistent f32 h slice
    __shared__ float sh_b[6][32];               // bias slices
    __shared__ float sh_bt[16];

    if (tid < 32) {
        sh_b[0][tid] = P.bih[j0 + tid];
        sh_b[1][tid] = P.bih[512 + j0 + tid];
        sh_b[2][tid] = P.bih[1024 + j0 + tid];
        sh_b[3][tid] = P.bhh[j0 + tid];
        sh_b[4][tid] = P.bhh[512 + j0 + tid];
        sh_b[5][tid] = P.bhh[1024 + j0 + tid];
    }
    if (tid < 16) sh_bt[tid] = P.bt[n0 + tid];
    sh_hf[tid] = 0.f; sh_hf[tid + 256] = 0.f;
    __syncthreads();

    int ep = 0;
    for (int t = 0; t < NT; ++t) {
        // ================= stage h[m0..m0+15][0..511] into LDS (coherent) =========
        {
            int q0 = tid, q1 = tid + 256, q2 = tid + 512, q3 = tid + 768;
            const unsigned short* g0 = P.hbf + (size_t)(m0 + (q0 >> 6)) * NH + (q0 & 63) * 8;
            const unsigned short* g1 = P.hbf + (size_t)(m0 + (q1 >> 6)) * NH + (q1 & 63) * 8;
            const unsigned short* g2 = P.hbf + (size_t)(m0 + (q2 >> 6)) * NH + (q2 & 63) * 8;
            const unsigned short* g3 = P.hbf + (size_t)(m0 + (q3 >> 6)) * NH + (q3 & 63) * 8;
            uintx4 r0, r1, r2, r3;
            ldg4_coh(g0, g1, g2, g3, r0, r1, r2, r3);
            *(uintx4*)&sh_h[(q0 >> 6) * 512 + (((q0 & 63) * 8) ^ (((q0 >> 6) & 7) * 8))] = r0;
            *(uintx4*)&sh_h[(q1 >> 6) * 512 + (((q1 & 63) * 8) ^ (((q1 >> 6) & 7) * 8))] = r1;
            *(uintx4*)&sh_h[(q2 >> 6) * 512 + (((q2 & 63) * 8) ^ (((q2 >> 6) & 7) * 8))] = r2;
            *(uintx4*)&sh_h[(q3 >> 6) * 512 + (((q3 & 63) * 8) ^ (((q3 >> 6) & 7) * 8))] = r3;
        }
        __syncthreads();

        // ================= Phase A =================
        if (w < 3) {
            // gh[16 x 32] for gate w (cols w*512 + j0 .. +31), K = 512
            floatx4 a0 = (floatx4){0.f,0.f,0.f,0.f};
            floatx4 a1 = (floatx4){0.f,0.f,0.f,0.f};
            const unsigned short* B0 = P.Whhb + (size_t)(w * 512 + j0 + lr) * NH + lk;
            const unsigned short* B1 = B0 + (size_t)16 * NH;
            #pragma unroll
            for (int kb = 0; kb < NH; kb += 32) {
                short8 a  = *(const short8*)&sh_h[lr * 512 + ((kb + lk) ^ ((lr & 7) * 8))];
                short8 b0 = *(const short8*)(B0 + kb);
                short8 b1 = *(const short8*)(B1 + kb);
                a0 = MFMA(a, b0, a0, 0, 0, 0);
                a1 = MFMA(a, b1, a1, 0, 0, 0);
            }
            #pragma unroll
            for (int rg = 0; rg < 4; ++rg) {
                int row = lkrow * 4 + rg;
                sh_gh[row * GHP + w * 32 + lr]      = a0[rg];
                sh_gh[row * GHP + w * 32 + 16 + lr] = a1[rg];
            }
        } else {
            // x'[16 x 16] tile at (m0, n0), K = 512 (h) + 160 (x)
            floatx4 acc = (floatx4){0.f,0.f,0.f,0.f};
            const unsigned short* Bw = P.Wthb + (size_t)(n0 + lr) * NH + lk;
            #pragma unroll
            for (int kb = 0; kb < NH; kb += 32) {
                short8 a = *(const short8*)&sh_h[lr * 512 + ((kb + lk) ^ ((lr & 7) * 8))];
                short8 b = *(const short8*)(Bw + kb);
                acc = MFMA(a, b, acc, 0, 0, 0);
            }
            const unsigned short* BX = P.Wtxb + (size_t)(n0 + lr) * 160 + lk;
            const size_t r = (size_t)(m0 + lr);
            #pragma unroll
            for (int c = 0; c < 5; ++c) {
                const float* pa = (c < 2) ? P.xl + (r * NT + t) * 64 + c * 32 + lk
                                : (c == 2)? P.xt + (r * NT + t) * 32 + lk
                                : (c == 3)? P.xw + (r * NT + t) * 32 + lk
                                          : P.xs + (r * NT + t) * 32 + lk;
                short8 a = ld8f32_bf(pa);
                short8 b = *(const short8*)(BX + c * 32);
                acc = MFMA(a, b, acc, 0, 0, 0);
            }
            #pragma unroll
            for (int rg = 0; rg < 4; ++rg) {
                int row = m0 + lkrow * 4 + rg;
                unsigned short v = f2bf(tanhf(acc[rg] + sh_bt[lr]));
                stg_short_coh(P.xpb + (size_t)row * NXP + n0 + lr, (unsigned)v);
            }
            vm_drain();
        }

        ++ep; gbar(P.l1, P.root, ep, bid);

        // ================= stage x'[m0..m0+15][0..255] into LDS (coherent) ========
        {
            int q0 = tid, q1 = tid + 256;
            const unsigned short* g0 = P.xpb + (size_t)(m0 + (q0 >> 5)) * NXP + (q0 & 31) * 8;
            const unsigned short* g1 = P.xpb + (size_t)(m0 + (q1 >> 5)) * NXP + (q1 & 31) * 8;
            uintx4 r0, r1;
            ldg2_coh(g0, g1, r0, r1);
            *(uintx4*)&sh_xp[(q0 >> 5) * 256 + (((q0 & 31) * 8) ^ (((q0 >> 5) & 7) * 8))] = r0;
            *(uintx4*)&sh_xp[(q1 >> 5) * 256 + (((q1 & 31) * 8) ^ (((q1 >> 5) & 7) * 8))] = r1;
        }
        __syncthreads();

        // ================= Phase B: gx (12 K-split units over 4 waves) ============
        #pragma unroll
        for (int i = 0; i < 3; ++i) {
            int u = w * 3 + i;
            int tile = u >> 1, kh = u & 1;
            int g = tile >> 1, sub = tile & 1;
            const unsigned short* Bp =
                P.Wihb + (size_t)(g * 512 + j0 + sub * 16 + lr) * NXP + kh * 128 + lk;
            floatx4 acc = (floatx4){0.f,0.f,0.f,0.f};
            #pragma unroll
            for (int kb = 0; kb < 128; kb += 32) {
                int k = kh * 128 + kb + lk;
                short8 a = *(const short8*)&sh_xp[lr * 256 + (k ^ ((lr & 7) * 8))];
                short8 b = *(const short8*)(Bp + kb);
                acc = MFMA(a, b, acc, 0, 0, 0);
            }
            #pragma unroll
            for (int rg = 0; rg < 4; ++rg) {
                int row = lkrow * 4 + rg;
                sh_gx[kh][row * GHP + g * 32 + sub * 16 + lr] = acc[rg];
            }
        }
        __syncthreads();

        // ================= gate epilogue: 2 outputs/thread =======================
        #pragma unroll
        for (int e = 0; e < 2; ++e) {
            int idx = tid + 256 * e;
            int row = idx >> 5, jj = idx & 31;
            float gxr = sh_gx[0][row * GHP + jj]      + sh_gx[1][row * GHP + jj];
            float gxz = sh_gx[0][row * GHP + 32 + jj] + sh_gx[1][row * GHP + 32 + jj];
            float gxn = sh_gx[0][row * GHP + 64 + jj] + sh_gx[1][row * GHP + 64 + jj];
            float ghr = sh_gh[row * GHP + jj];
            float ghz = sh_gh[row * GHP + 32 + jj];
            float ghn = sh_gh[row * GHP + 64 + jj];
            float rg_ = sigmoidf_(gxr + ghr + sh_b[0][jj] + sh_b[3][jj]);
            float zg  = sigmoidf_(gxz + ghz + sh_b[1][jj] + sh_b[4][jj]);
            float ng  = tanhf(gxn + sh_b[2][jj] + rg_ * (ghn + sh_b[5][jj]));
            float hold = sh_hf[row * 32 + jj];
            float hnew = (1.f - zg) * ng + zg * hold;
            sh_hf[row * 32 + jj] = hnew;
            stg_short_coh(P.hbf + (size_t)(m0 + row) * NH + j0 + jj, (unsigned)f2bf(hnew));
            if (t == NT - 1) P.out[(size_t)(m0 + row) * NH + j0 + jj] = hnew;
        }
        vm_drain();
        ++ep; gbar(P.l1, P.root, ep, bid);
    }
}

extern "C" void kernel_launch(void* const* d_in, const int* in_sizes, int n_in,
                              void* d_out, int out_size, void* d_ws, size_t ws_size,
                              hipStream_t stream)
{
    (void)in_sizes; (void)n_in; (void)out_size;
    const float* xl  = (const float*)d_in[0];
    const float* xt_ = (const float*)d_in[1];
    const float* xw  = (const float*)d_in[2];
    const float* xs  = (const float*)d_in[3];
    const float* Wih = (const float*)d_in[4];
    const float* Whh = (const float*)d_in[5];
    const float* bih = (const float*)d_in[6];
    const float* bhh = (const float*)d_in[7];
    const float* Wth = (const float*)d_in[8];
    const float* Wtx = (const float*)d_in[9];
    const float* bt  = (const float*)d_in[10];

    char* p = (char*)d_ws;
    int* l1   = (int*)p;                        p += 4096;   // 8 counters + root, padded
    unsigned short* hbf = (unsigned short*)p;   p += (size_t)NB * NH * 2;
    unsigned short* xpb = (unsigned short*)p;   p += (size_t)NB * NXP * 2;
    unsigned short* Wihb = (unsigned short*)p;  p += (size_t)1536 * 256 * 2;
    unsigned short* Whhb = (unsigned short*)p;  p += (size_t)1536 * 512 * 2;
    unsigned short* Wthb = (unsigned short*)p;  p += (size_t)256 * 512 * 2;
    unsigned short* Wtxb = (unsigned short*)p;  p += (size_t)256 * 160 * 2;
    if ((size_t)(p - (char*)d_ws) > ws_size) return;
    int* root = l1 + 8 * 64;

    k_cvt<<<256, 256, 0, stream>>>(Wih, Wihb, 1536 * 256);
    k_cvt<<<256, 256, 0, stream>>>(Whh, Whhb, 1536 * 512);
    k_cvt<<<64, 256, 0, stream>>>(Wth, Wthb, 256 * 512);
    k_cvt<<<32, 256, 0, stream>>>(Wtx, Wtxb, 256 * 160);
    hipMemsetAsync(l1, 0, 4096, stream);
    hipMemsetAsync(hbf, 0, (size_t)NB * NH * 2, stream);

    KParams P;
    P.xl = xl; P.xt = xt_; P.xw = xw; P.xs = xs;
    P.bih = bih; P.bhh = bhh; P.bt = bt;
    P.Wihb = Wihb; P.Whhb = Whhb; P.Wthb = Wthb; P.Wtxb = Wtxb;
    P.hbf = hbf; P.xpb = xpb;
    P.out = (float*)d_out; P.l1 = l1; P.root = root;

    void* args[] = { &P };
    if (hipLaunchCooperativeKernel((const void*)k_persist, dim3(256), dim3(256),
                                   args, 0, stream) != hipSuccess) {
        k_persist<<<256, 256, 0, stream>>>(P);
    }
}

// Round 5
// 3480.335 us; speedup vs baseline: 6.3761x; 2.0279x over previous
//
#include <hip/hip_runtime.h>
#include <math.h>

typedef __attribute__((ext_vector_type(8))) short short8;
typedef __attribute__((ext_vector_type(4))) float floatx4;
typedef __attribute__((ext_vector_type(4))) unsigned uintx4;

#define NB 256
#define NH 512
#define NXP 256
#define NT 512
#define GHP 100

#define MFMA __builtin_amdgcn_mfma_f32_16x16x32_bf16

__device__ __forceinline__ unsigned short f2bf(float f) {
    union { float f; unsigned u; } x; x.f = f;
    unsigned r = x.u + 0x7FFFu + ((x.u >> 16) & 1u);
    return (unsigned short)(r >> 16);
}
__device__ __forceinline__ float sigmoidf_(float x) { return 1.0f / (1.0f + __expf(-x)); }

__device__ __forceinline__ short8 cvt8(float4 u, float4 v) {
    short8 r;
    r[0] = (short)f2bf(u.x); r[1] = (short)f2bf(u.y);
    r[2] = (short)f2bf(u.z); r[3] = (short)f2bf(u.w);
    r[4] = (short)f2bf(v.x); r[5] = (short)f2bf(v.y);
    r[6] = (short)f2bf(v.z); r[7] = (short)f2bf(v.w);
    return r;
}

// ---- device-coherent data ops (sc0 sc1) — PROVEN cross-XCD by round 3 ----
__device__ __forceinline__ void ldg4_c(const void* p0, const void* p1,
                                       const void* p2, const void* p3,
                                       uintx4& r0, uintx4& r1, uintx4& r2, uintx4& r3) {
    asm volatile(
        "global_load_dwordx4 %0, %4, off sc0 sc1\n\t"
        "global_load_dwordx4 %1, %5, off sc0 sc1\n\t"
        "global_load_dwordx4 %2, %6, off sc0 sc1\n\t"
        "global_load_dwordx4 %3, %7, off sc0 sc1\n\t"
        "s_waitcnt vmcnt(0)"
        : "=&v"(r0), "=&v"(r1), "=&v"(r2), "=&v"(r3)
        : "v"(p0), "v"(p1), "v"(p2), "v"(p3) : "memory");
}
__device__ __forceinline__ void ldg2_c(const void* p0, const void* p1,
                                       uintx4& r0, uintx4& r1) {
    asm volatile(
        "global_load_dwordx4 %0, %2, off sc0 sc1\n\t"
        "global_load_dwordx4 %1, %3, off sc0 sc1\n\t"
        "s_waitcnt vmcnt(0)"
        : "=&v"(r0), "=&v"(r1) : "v"(p0), "v"(p1) : "memory");
}
__device__ __forceinline__ void st16_c(void* p, unsigned v) {
    asm volatile("global_store_short %0, %1, off sc0 sc1" :: "v"(p), "v"(v) : "memory");
}
__device__ __forceinline__ void st32_c(void* p, unsigned v) {
    asm volatile("global_store_dword %0, %1, off sc0 sc1" :: "v"(p), "v"(v) : "memory");
}
__device__ __forceinline__ void vm_drain() {
    asm volatile("s_waitcnt vmcnt(0)" ::: "memory");
}

// ---- flag sync: relaxed agent atomics — PROVEN by round 3 ----
__device__ __forceinline__ void poll16(const int* f, int target, int lane) {
    const int* fp = f + (lane & 15);
    for (;;) {
        int v = __hip_atomic_load(fp, __ATOMIC_RELAXED, __HIP_MEMORY_SCOPE_AGENT);
        if (__ballot(v < target) == 0ull) break;
        __builtin_amdgcn_s_sleep(1);
    }
}
__device__ __forceinline__ void flag_bump(int* f) {
    __hip_atomic_fetch_add(f, 1, __ATOMIC_RELAXED, __HIP_MEMORY_SCOPE_AGENT);
}

__global__ void k_cvt(const float* __restrict__ src, unsigned short* __restrict__ dst, int n) {
    int i = blockIdx.x * blockDim.x + threadIdx.x;
    int stride = gridDim.x * blockDim.x;
    for (; i < n; i += stride) dst[i] = f2bf(src[i]);
}

struct KParams {
    const float *xl, *xt, *xw, *xs;
    const float *bih, *bhh, *bt;
    const unsigned short *Wihb, *Whhb, *Wthb, *Wtxb;
    unsigned short *hb0, *hb1, *xpb;
    float *out;
    int *flags;
};

__global__ __launch_bounds__(256, 1)
void k_persist(KParams P)
{
    const int tid   = threadIdx.x;
    const int w     = tid >> 6;
    const int lane  = tid & 63;
    const int lr    = lane & 15;
    const int lkrow = lane >> 4;
    const int lk    = lkrow * 8;
    const int bid   = blockIdx.x;
    // group = 16 blocks sharing batch rows m0..m0+15; member jc owns h-cols j0..j0+31
    const int grp   = bid >> 4;
    const int jc    = bid & 15;
    const int m0    = grp * 16;
    const int j0    = jc * 32;
    const int n0    = jc * 16;

    int* gfl = P.flags + grp * 64;      // 256 B per group
    int* hfl = gfl;                     // [16] h-ready epochs
    int* xfl = gfl + 16;                // [16] x'-ready epochs

    __shared__ unsigned short sh_h[16 * 512];
    __shared__ unsigned short sh_xp[16 * 256];
    __shared__ float sh_gh[16 * GHP];
    __shared__ float sh_gx[2][16 * GHP];
    __shared__ float sh_hf[16 * 32];
    __shared__ float sh_b[6][32];
    __shared__ float sh_bt[16];

    if (tid < 32) {
        sh_b[0][tid] = P.bih[j0 + tid];
        sh_b[1][tid] = P.bih[512 + j0 + tid];
        sh_b[2][tid] = P.bih[1024 + j0 + tid];
        sh_b[3][tid] = P.bhh[j0 + tid];
        sh_b[4][tid] = P.bhh[512 + j0 + tid];
        sh_b[5][tid] = P.bhh[1024 + j0 + tid];
    }
    if (tid < 16) sh_bt[tid] = P.bt[n0 + tid];
    sh_hf[tid] = 0.f; sh_hf[tid + 256] = 0.f;

    // ---- hoist step-invariant MFMA B-operands into registers ----
    short8 bWih[3][4];     // gx units: u = w*3+i -> (tile = u>>1, khalf = u&1)
    short8 bWhh[2][16];    // w<3: two Whh 16-col tiles; w==3: [0]=Wth, [1][0..4]=Wtx
    #pragma unroll
    for (int i = 0; i < 3; ++i) {
        const int u = w * 3 + i, tile = u >> 1, kh = u & 1;
        const int g = tile >> 1, sub = tile & 1;
        const unsigned short* bp =
            P.Wihb + (size_t)(g * 512 + j0 + sub * 16 + lr) * NXP + kh * 128 + lk;
        #pragma unroll
        for (int kb = 0; kb < 4; ++kb) bWih[i][kb] = *(const short8*)(bp + kb * 32);
    }
    if (w < 3) {
        #pragma unroll
        for (int sub = 0; sub < 2; ++sub) {
            const unsigned short* bp =
                P.Whhb + (size_t)(w * 512 + j0 + sub * 16 + lr) * NH + lk;
            #pragma unroll
            for (int kb = 0; kb < 16; ++kb) bWhh[sub][kb] = *(const short8*)(bp + kb * 32);
        }
    } else {
        const unsigned short* bp = P.Wthb + (size_t)(n0 + lr) * NH + lk;
        #pragma unroll
        for (int kb = 0; kb < 16; ++kb) bWhh[0][kb] = *(const short8*)(bp + kb * 32);
        const unsigned short* bx = P.Wtxb + (size_t)(n0 + lr) * 160 + lk;
        #pragma unroll
        for (int c = 0; c < 5; ++c) bWhh[1][c] = *(const short8*)(bx + c * 32);
    }
    __syncthreads();

    for (int t = 0; t < NT; ++t) {
        const unsigned short* hsrc = (t & 1) ? P.hb1 : P.hb0;
        unsigned short*       hdst = (t & 1) ? P.hb0 : P.hb1;

        // issue x-input loads early (plain cached; overlaps the h-poll)
        float4 xq[5][2];
        if (w == 3) {
            const size_t r = (size_t)(m0 + lr);
            #pragma unroll
            for (int c = 0; c < 5; ++c) {
                const float* pa = (c < 2) ? P.xl + (r * NT + t) * 64 + c * 32 + lk
                                : (c == 2)? P.xt + (r * NT + t) * 32 + lk
                                : (c == 3)? P.xw + (r * NT + t) * 32 + lk
                                          : P.xs + (r * NT + t) * 32 + lk;
                xq[c][0] = *(const float4*)pa;
                xq[c][1] = *(const float4*)(pa + 4);
            }
        }

        // ---- wait for h_t (16 producer flags), stage h -> LDS ----
        poll16(hfl, t, lane);
        {
            const int row = tid >> 4, c = (tid & 15) * 32;
            const unsigned short* gp = hsrc + (size_t)(m0 + row) * NH + c;
            uintx4 r0, r1, r2, r3;
            ldg4_c(gp, gp + 8, gp + 16, gp + 24, r0, r1, r2, r3);
            const int sw = (row & 7) * 8;
            *(uintx4*)&sh_h[row * 512 + ((c +  0) ^ sw)] = r0;
            *(uintx4*)&sh_h[row * 512 + ((c +  8) ^ sw)] = r1;
            *(uintx4*)&sh_h[row * 512 + ((c + 16) ^ sw)] = r2;
            *(uintx4*)&sh_h[row * 512 + ((c + 24) ^ sw)] = r3;
        }
        __syncthreads();

        // ---- Phase A: gh (waves 0-2) / x' (wave 3) ----
        if (w < 3) {
            floatx4 a0 = (floatx4){0.f,0.f,0.f,0.f};
            floatx4 a1 = (floatx4){0.f,0.f,0.f,0.f};
            const int sw = (lr & 7) * 8;
            #pragma unroll
            for (int kb = 0; kb < 16; ++kb) {
                short8 a = *(const short8*)&sh_h[lr * 512 + ((kb * 32 + lk) ^ sw)];
                a0 = MFMA(a, bWhh[0][kb], a0, 0, 0, 0);
                a1 = MFMA(a, bWhh[1][kb], a1, 0, 0, 0);
            }
            #pragma unroll
            for (int rg = 0; rg < 4; ++rg) {
                const int row = lkrow * 4 + rg;
                sh_gh[row * GHP + w * 32 + lr]      = a0[rg];
                sh_gh[row * GHP + w * 32 + 16 + lr] = a1[rg];
            }
        } else {
            floatx4 acc = (floatx4){0.f,0.f,0.f,0.f};
            const int sw = (lr & 7) * 8;
            #pragma unroll
            for (int kb = 0; kb < 16; ++kb) {
                short8 a = *(const short8*)&sh_h[lr * 512 + ((kb * 32 + lk) ^ sw)];
                acc = MFMA(a, bWhh[0][kb], acc, 0, 0, 0);
            }
            #pragma unroll
            for (int c = 0; c < 5; ++c) {
                short8 a = cvt8(xq[c][0], xq[c][1]);
                acc = MFMA(a, bWhh[1][c], acc, 0, 0, 0);
            }
            #pragma unroll
            for (int rg = 0; rg < 4; ++rg) {
                const int row = lkrow * 4 + rg;
                unsigned short v = f2bf(tanhf(acc[rg] + sh_bt[lr]));
                st16_c(P.xpb + (size_t)(m0 + row) * NXP + n0 + lr, (unsigned)v);
            }
            vm_drain();
            if (lane == 0) flag_bump(xfl + jc);
        }

        // ---- wait for x'_t, stage x' -> LDS ----
        poll16(xfl, t + 1, lane);
        {
            const int row = tid >> 4, c = (tid & 15) * 16;
            const unsigned short* gp = P.xpb + (size_t)(m0 + row) * NXP + c;
            uintx4 r0, r1;
            ldg2_c(gp, gp + 8, r0, r1);
            const int sw = (row & 7) * 8;
            *(uintx4*)&sh_xp[row * 256 + ((c + 0) ^ sw)] = r0;
            *(uintx4*)&sh_xp[row * 256 + ((c + 8) ^ sw)] = r1;
        }
        __syncthreads();

        // ---- Phase B: gx ----
        #pragma unroll
        for (int i = 0; i < 3; ++i) {
            const int u = w * 3 + i, tile = u >> 1, kh = u & 1;
            const int g = tile >> 1, sub = tile & 1;
            floatx4 acc = (floatx4){0.f,0.f,0.f,0.f};
            const int sw = (lr & 7) * 8;
            #pragma unroll
            for (int kb = 0; kb < 4; ++kb) {
                short8 a = *(const short8*)&sh_xp[lr * 256 + ((kh * 128 + kb * 32 + lk) ^ sw)];
                acc = MFMA(a, bWih[i][kb], acc, 0, 0, 0);
            }
            #pragma unroll
            for (int rg = 0; rg < 4; ++rg) {
                const int row = lkrow * 4 + rg;
                sh_gx[kh][row * GHP + g * 32 + sub * 16 + lr] = acc[rg];
            }
        }
        __syncthreads();

        // ---- epilogue: gates + h update (2 adjacent cols/thread) ----
        {
            const int row = tid >> 4, jj = (tid & 15) * 2;
            float hn[2];
            #pragma unroll
            for (int jo = 0; jo < 2; ++jo) {
                const int j = jj + jo;
                float gxr = sh_gx[0][row * GHP + j]      + sh_gx[1][row * GHP + j];
                float gxz = sh_gx[0][row * GHP + 32 + j] + sh_gx[1][row * GHP + 32 + j];
                float gxn = sh_gx[0][row * GHP + 64 + j] + sh_gx[1][row * GHP + 64 + j];
                float ghr = sh_gh[row * GHP + j];
                float ghz = sh_gh[row * GHP + 32 + j];
                float ghn = sh_gh[row * GHP + 64 + j];
                float rg_ = sigmoidf_(gxr + ghr + sh_b[0][j] + sh_b[3][j]);
                float zg  = sigmoidf_(gxz + ghz + sh_b[1][j] + sh_b[4][j]);
                float ng  = tanhf(gxn + sh_b[2][j] + rg_ * (ghn + sh_b[5][j]));
                float hold = sh_hf[row * 32 + j];
                hn[jo] = (1.f - zg) * ng + zg * hold;
                sh_hf[row * 32 + j] = hn[jo];
            }
            unsigned d = (unsigned)f2bf(hn[0]) | ((unsigned)f2bf(hn[1]) << 16);
            st32_c(hdst + (size_t)(m0 + row) * NH + j0 + jj, d);
            if (t == NT - 1) {
                float2 o; o.x = hn[0]; o.y = hn[1];
                *(float2*)&P.out[(size_t)(m0 + row) * NH + j0 + jj] = o;
            }
            vm_drain();
        }
        __syncthreads();
        if (tid == 0) flag_bump(hfl + jc);
    }
}

extern "C" void kernel_launch(void* const* d_in, const int* in_sizes, int n_in,
                              void* d_out, int out_size, void* d_ws, size_t ws_size,
                              hipStream_t stream)
{
    (void)in_sizes; (void)n_in; (void)out_size;
    const float* xl  = (const float*)d_in[0];
    const float* xt_ = (const float*)d_in[1];
    const float* xw  = (const float*)d_in[2];
    const float* xs  = (const float*)d_in[3];
    const float* Wih = (const float*)d_in[4];
    const float* Whh = (const float*)d_in[5];
    const float* bih = (const float*)d_in[6];
    const float* bhh = (const float*)d_in[7];
    const float* Wth = (const float*)d_in[8];
    const float* Wtx = (const float*)d_in[9];
    const float* bt  = (const float*)d_in[10];

    char* p = (char*)d_ws;
    int* flags = (int*)p;                       p += 16384;
    unsigned short* hb0 = (unsigned short*)p;   p += (size_t)NB * NH * 2;
    unsigned short* hb1 = (unsigned short*)p;   p += (size_t)NB * NH * 2;
    unsigned short* xpb = (unsigned short*)p;   p += (size_t)NB * NXP * 2;
    unsigned short* Wihb = (unsigned short*)p;  p += (size_t)1536 * 256 * 2;
    unsigned short* Whhb = (unsigned short*)p;  p += (size_t)1536 * 512 * 2;
    unsigned short* Wthb = (unsigned short*)p;  p += (size_t)256 * 512 * 2;
    unsigned short* Wtxb = (unsigned short*)p;  p += (size_t)256 * 160 * 2;
    if ((size_t)(p - (char*)d_ws) > ws_size) return;

    k_cvt<<<256, 256, 0, stream>>>(Wih, Wihb, 1536 * 256);
    k_cvt<<<256, 256, 0, stream>>>(Whh, Whhb, 1536 * 512);
    k_cvt<<<64, 256, 0, stream>>>(Wth, Wthb, 256 * 512);
    k_cvt<<<32, 256, 0, stream>>>(Wtx, Wtxb, 256 * 160);
    hipMemsetAsync(flags, 0, 16384, stream);
    hipMemsetAsync(hb0, 0, (size_t)NB * NH * 2, stream);

    KParams P;
    P.xl = xl; P.xt = xt_; P.xw = xw; P.xs = xs;
    P.bih = bih; P.bhh = bhh; P.bt = bt;
    P.Wihb = Wihb; P.Whhb = Whhb; P.Wthb = Wthb; P.Wtxb = Wtxb;
    P.hb0 = hb0; P.hb1 = hb1; P.xpb = xpb;
    P.out = (float*)d_out; P.flags = flags;

    void* args[] = { &P };
    if (hipLaunchCooperativeKernel((const void*)k_persist, dim3(256), dim3(256),
                                   args, 0, stream) != hipSuccess) {
        k_persist<<<256, 256, 0, stream>>>(P);
    }
}

// Round 7
// 3243.559 us; speedup vs baseline: 6.8416x; 1.0730x over previous
//
#include <hip/hip_runtime.h>
#include <math.h>

typedef __attribute__((ext_vector_type(8))) short short8;
typedef __attribute__((ext_vector_type(4))) float floatx4;
typedef __attribute__((ext_vector_type(4))) unsigned uintx4;

#define NB 256
#define NH 512
#define NXP 256
#define NT 512
#define GHP 100

#define MFMA __builtin_amdgcn_mfma_f32_16x16x32_bf16

__device__ __forceinline__ unsigned short f2bf(float f) {
    union { float f; unsigned u; } x; x.f = f;
    unsigned r = x.u + 0x7FFFu + ((x.u >> 16) & 1u);
    return (unsigned short)(r >> 16);
}
__device__ __forceinline__ float sigmoidf_(float x) { return 1.0f / (1.0f + __expf(-x)); }

__device__ __forceinline__ short8 cvt8(float4 u, float4 v) {
    short8 r;
    r[0] = (short)f2bf(u.x); r[1] = (short)f2bf(u.y);
    r[2] = (short)f2bf(u.z); r[3] = (short)f2bf(u.w);
    r[4] = (short)f2bf(v.x); r[5] = (short)f2bf(v.y);
    r[6] = (short)f2bf(v.z); r[7] = (short)f2bf(v.w);
    return r;
}

// ---- device-coherent data ops (sc0 sc1) — PROVEN cross-XCD (rounds 3/5).
//      sc0-only fast path is REFUTED (round 6: stale reads) — do not revisit.
__device__ __forceinline__ void ldg4_c(const void* p0, const void* p1,
                                       const void* p2, const void* p3,
                                       uintx4& r0, uintx4& r1, uintx4& r2, uintx4& r3) {
    asm volatile(
        "global_load_dwordx4 %0, %4, off sc0 sc1\n\t"
        "global_load_dwordx4 %1, %5, off sc0 sc1\n\t"
        "global_load_dwordx4 %2, %6, off sc0 sc1\n\t"
        "global_load_dwordx4 %3, %7, off sc0 sc1\n\t"
        "s_waitcnt vmcnt(0)"
        : "=&v"(r0), "=&v"(r1), "=&v"(r2), "=&v"(r3)
        : "v"(p0), "v"(p1), "v"(p2), "v"(p3) : "memory");
}
__device__ __forceinline__ void ldg2_c(const void* p0, const void* p1,
                                       uintx4& r0, uintx4& r1) {
    asm volatile(
        "global_load_dwordx4 %0, %2, off sc0 sc1\n\t"
        "global_load_dwordx4 %1, %3, off sc0 sc1\n\t"
        "s_waitcnt vmcnt(0)"
        : "=&v"(r0), "=&v"(r1) : "v"(p0), "v"(p1) : "memory");
}
__device__ __forceinline__ void st16_c(void* p, unsigned v) {
    asm volatile("global_store_short %0, %1, off sc0 sc1" :: "v"(p), "v"(v) : "memory");
}
__device__ __forceinline__ void st32_c(void* p, unsigned v) {
    asm volatile("global_store_dword %0, %1, off sc0 sc1" :: "v"(p), "v"(v) : "memory");
}
__device__ __forceinline__ void vm_drain() {
    asm volatile("s_waitcnt vmcnt(0)" ::: "memory");
}

// ---- flag fabric: relaxed agent atomics (proven), SINGLE WRITER per flag,
//      one flag per 64B line: flag i lives at f[i*16].
__device__ __forceinline__ void flag_set(int* f, int v) {
    __hip_atomic_store(f, v, __ATOMIC_RELAXED, __HIP_MEMORY_SCOPE_AGENT);
}
__device__ __forceinline__ void poll16(const int* f, int target, int lane) {
    const int* fp = f + (lane & 15) * 16;
    for (;;) {
        int v = __hip_atomic_load(fp, __ATOMIC_RELAXED, __HIP_MEMORY_SCOPE_AGENT);
        if (__ballot(v < target) == 0ull) break;
        __builtin_amdgcn_s_sleep(1);
    }
}

__global__ void k_cvt(const float* __restrict__ src, unsigned short* __restrict__ dst, int n) {
    int i = blockIdx.x * blockDim.x + threadIdx.x;
    int stride = gridDim.x * blockDim.x;
    for (; i < n; i += stride) dst[i] = f2bf(src[i]);
}

struct KParams {
    const float *xl, *xt, *xw, *xs;
    const float *bih, *bhh, *bt;
    const unsigned short *Wihb, *Whhb, *Wthb, *Wtxb;
    unsigned short *hb0, *hb1, *xpb;
    float *out;
    int *flags;
};

__global__ __launch_bounds__(256, 1)
void k_persist(KParams P)
{
    const int tid   = threadIdx.x;
    const int w     = tid >> 6;
    const int lane  = tid & 63;
    const int lr    = lane & 15;
    const int lkrow = lane >> 4;
    const int lk    = lkrow * 8;
    const int bid   = blockIdx.x;
    const int grp   = bid >> 4;
    const int jc    = bid & 15;
    const int m0    = grp * 16;
    const int j0    = jc * 32;
    const int n0    = jc * 16;

    // per-group flag region: 512 ints (2048 B)
    //   hfl: flag i at [i*16]   (64B line each)
    //   xfl: flag i at [256 + i*16]
    int* gfl = P.flags + grp * 512;
    int* hfl = gfl;
    int* xfl = gfl + 256;

    __shared__ unsigned short sh_h[16 * 512];
    __shared__ unsigned short sh_xp[16 * 256];
    __shared__ float sh_gh[16 * GHP];
    __shared__ float sh_gx[2][16 * GHP];
    __shared__ float sh_hf[16 * 32];
    __shared__ float sh_b[6][32];
    __shared__ float sh_bt[16];

    if (tid < 32) {
        sh_b[0][tid] = P.bih[j0 + tid];
        sh_b[1][tid] = P.bih[512 + j0 + tid];
        sh_b[2][tid] = P.bih[1024 + j0 + tid];
        sh_b[3][tid] = P.bhh[j0 + tid];
        sh_b[4][tid] = P.bhh[512 + j0 + tid];
        sh_b[5][tid] = P.bhh[1024 + j0 + tid];
    }
    if (tid < 16) sh_bt[tid] = P.bt[n0 + tid];
    sh_hf[tid] = 0.f; sh_hf[tid + 256] = 0.f;

    // ---- hoist step-invariant MFMA B-operands into registers ----
    short8 bWih[3][4];
    short8 bWhh[2][16];
    #pragma unroll
    for (int i = 0; i < 3; ++i) {
        const int u = w * 3 + i, tile = u >> 1, kh = u & 1;
        const int g = tile >> 1, sub = tile & 1;
        const unsigned short* bp =
            P.Wihb + (size_t)(g * 512 + j0 + sub * 16 + lr) * NXP + kh * 128 + lk;
        #pragma unroll
        for (int kb = 0; kb < 4; ++kb) bWih[i][kb] = *(const short8*)(bp + kb * 32);
    }
    if (w < 3) {
        #pragma unroll
        for (int sub = 0; sub < 2; ++sub) {
            const unsigned short* bp =
                P.Whhb + (size_t)(w * 512 + j0 + sub * 16 + lr) * NH + lk;
            #pragma unroll
            for (int kb = 0; kb < 16; ++kb) bWhh[sub][kb] = *(const short8*)(bp + kb * 32);
        }
    } else {
        const unsigned short* bp = P.Wthb + (size_t)(n0 + lr) * NH + lk;
        #pragma unroll
        for (int kb = 0; kb < 16; ++kb) bWhh[0][kb] = *(const short8*)(bp + kb * 32);
        const unsigned short* bx = P.Wtxb + (size_t)(n0 + lr) * 160 + lk;
        #pragma unroll
        for (int c = 0; c < 5; ++c) bWhh[1][c] = *(const short8*)(bx + c * 32);
    }
    __syncthreads();

    for (int t = 0; t < NT; ++t) {
        const unsigned short* hsrc = (t & 1) ? P.hb1 : P.hb0;
        unsigned short*       hdst = (t & 1) ? P.hb0 : P.hb1;

        // x-input loads early (plain cached; overlaps the h-poll)
        float4 xq[5][2];
        if (w == 3) {
            const size_t r = (size_t)(m0 + lr);
            #pragma unroll
            for (int c = 0; c < 5; ++c) {
                const float* pa = (c < 2) ? P.xl + (r * NT + t) * 64 + c * 32 + lk
                                : (c == 2)? P.xt + (r * NT + t) * 32 + lk
                                : (c == 3)? P.xw + (r * NT + t) * 32 + lk
                                          : P.xs + (r * NT + t) * 32 + lk;
                xq[c][0] = *(const float4*)pa;
                xq[c][1] = *(const float4*)(pa + 4);
            }
        }

        // ---- wait for h_t (16 producer flags), stage h -> LDS ----
        poll16(hfl, t, lane);
        {
            const int row = tid >> 4, c = (tid & 15) * 32;
            const unsigned short* gp = hsrc + (size_t)(m0 + row) * NH + c;
            uintx4 r0, r1, r2, r3;
            ldg4_c(gp, gp + 8, gp + 16, gp + 24, r0, r1, r2, r3);
            const int sw = (row & 7) * 8;
            *(uintx4*)&sh_h[row * 512 + ((c +  0) ^ sw)] = r0;
            *(uintx4*)&sh_h[row * 512 + ((c +  8) ^ sw)] = r1;
            *(uintx4*)&sh_h[row * 512 + ((c + 16) ^ sw)] = r2;
            *(uintx4*)&sh_h[row * 512 + ((c + 24) ^ sw)] = r3;
        }
        __syncthreads();

        // ---- Phase A: gh (waves 0-2) / x' (wave 3) ----
        if (w < 3) {
            floatx4 a0 = (floatx4){0.f,0.f,0.f,0.f};
            floatx4 a1 = (floatx4){0.f,0.f,0.f,0.f};
            const int sw = (lr & 7) * 8;
            #pragma unroll
            for (int kb = 0; kb < 16; ++kb) {
                short8 a = *(const short8*)&sh_h[lr * 512 + ((kb * 32 + lk) ^ sw)];
                a0 = MFMA(a, bWhh[0][kb], a0, 0, 0, 0);
                a1 = MFMA(a, bWhh[1][kb], a1, 0, 0, 0);
            }
            #pragma unroll
            for (int rg = 0; rg < 4; ++rg) {
                const int row = lkrow * 4 + rg;
                sh_gh[row * GHP + w * 32 + lr]      = a0[rg];
                sh_gh[row * GHP + w * 32 + 16 + lr] = a1[rg];
            }
        } else {
            floatx4 acc = (floatx4){0.f,0.f,0.f,0.f};
            const int sw = (lr & 7) * 8;
            #pragma unroll
            for (int kb = 0; kb < 16; ++kb) {
                short8 a = *(const short8*)&sh_h[lr * 512 + ((kb * 32 + lk) ^ sw)];
                acc = MFMA(a, bWhh[0][kb], acc, 0, 0, 0);
            }
            #pragma unroll
            for (int c = 0; c < 5; ++c) {
                short8 a = cvt8(xq[c][0], xq[c][1]);
                acc = MFMA(a, bWhh[1][c], acc, 0, 0, 0);
            }
            #pragma unroll
            for (int rg = 0; rg < 4; ++rg) {
                const int row = lkrow * 4 + rg;
                unsigned short v = f2bf(tanhf(acc[rg] + sh_bt[lr]));
                st16_c(P.xpb + (size_t)(m0 + row) * NXP + n0 + lr, (unsigned)v);
            }
            vm_drain();
            if (lane == 0) flag_set(xfl + jc * 16, t + 1);
        }

        // ---- wait for x'_t, stage x' -> LDS ----
        poll16(xfl, t + 1, lane);
        {
            const int row = tid >> 4, c = (tid & 15) * 16;
            const unsigned short* gp = P.xpb + (size_t)(m0 + row) * NXP + c;
            uintx4 r0, r1;
            ldg2_c(gp, gp + 8, r0, r1);
            const int sw = (row & 7) * 8;
            *(uintx4*)&sh_xp[row * 256 + ((c + 0) ^ sw)] = r0;
            *(uintx4*)&sh_xp[row * 256 + ((c + 8) ^ sw)] = r1;
        }
        __syncthreads();

        // ---- Phase B: gx ----
        #pragma unroll
        for (int i = 0; i < 3; ++i) {
            const int u = w * 3 + i, tile = u >> 1, kh = u & 1;
            const int g = tile >> 1, sub = tile & 1;
            floatx4 acc = (floatx4){0.f,0.f,0.f,0.f};
            const int sw = (lr & 7) * 8;
            #pragma unroll
            for (int kb = 0; kb < 4; ++kb) {
                short8 a = *(const short8*)&sh_xp[lr * 256 + ((kh * 128 + kb * 32 + lk) ^ sw)];
                acc = MFMA(a, bWih[i][kb], acc, 0, 0, 0);
            }
            #pragma unroll
            for (int rg = 0; rg < 4; ++rg) {
                const int row = lkrow * 4 + rg;
                sh_gx[kh][row * GHP + g * 32 + sub * 16 + lr] = acc[rg];
            }
        }
        __syncthreads();

        // ---- epilogue: gates + h update (2 adjacent cols/thread) ----
        {
            const int row = tid >> 4, jj = (tid & 15) * 2;
            float hn[2];
            #pragma unroll
            for (int jo = 0; jo < 2; ++jo) {
                const int j = jj + jo;
                float gxr = sh_gx[0][row * GHP + j]      + sh_gx[1][row * GHP + j];
                float gxz = sh_gx[0][row * GHP + 32 + j] + sh_gx[1][row * GHP + 32 + j];
                float gxn = sh_gx[0][row * GHP + 64 + j] + sh_gx[1][row * GHP + 64 + j];
                float ghr = sh_gh[row * GHP + j];
                float ghz = sh_gh[row * GHP + 32 + j];
                float ghn = sh_gh[row * GHP + 64 + j];
                float rg_ = sigmoidf_(gxr + ghr + sh_b[0][j] + sh_b[3][j]);
                float zg  = sigmoidf_(gxz + ghz + sh_b[1][j] + sh_b[4][j]);
                float ng  = tanhf(gxn + sh_b[2][j] + rg_ * (ghn + sh_b[5][j]));
                float hold = sh_hf[row * 32 + j];
                hn[jo] = (1.f - zg) * ng + zg * hold;
                sh_hf[row * 32 + j] = hn[jo];
            }
            unsigned d = (unsigned)f2bf(hn[0]) | ((unsigned)f2bf(hn[1]) << 16);
            st32_c(hdst + (size_t)(m0 + row) * NH + j0 + jj, d);
            if (t == NT - 1) {
                float2 o; o.x = hn[0]; o.y = hn[1];
                *(float2*)&P.out[(size_t)(m0 + row) * NH + j0 + jj] = o;
            }
            vm_drain();
        }
        __syncthreads();
        if (tid == 0) flag_set(hfl + jc * 16, t + 1);
    }
}

extern "C" void kernel_launch(void* const* d_in, const int* in_sizes, int n_in,
                              void* d_out, int out_size, void* d_ws, size_t ws_size,
                              hipStream_t stream)
{
    (void)in_sizes; (void)n_in; (void)out_size;
    const float* xl  = (const float*)d_in[0];
    const float* xt_ = (const float*)d_in[1];
    const float* xw  = (const float*)d_in[2];
    const float* xs  = (const float*)d_in[3];
    const float* Wih = (const float*)d_in[4];
    const float* Whh = (const float*)d_in[5];
    const float* bih = (const float*)d_in[6];
    const float* bhh = (const float*)d_in[7];
    const float* Wth = (const float*)d_in[8];
    const float* Wtx = (const float*)d_in[9];
    const float* bt  = (const float*)d_in[10];

    char* p = (char*)d_ws;
    int* flags = (int*)p;                       p += 32768;   // 16 groups x 2048 B
    unsigned short* hb0 = (unsigned short*)p;   p += (size_t)NB * NH * 2;
    unsigned short* hb1 = (unsigned short*)p;   p += (size_t)NB * NH * 2;
    unsigned short* xpb = (unsigned short*)p;   p += (size_t)NB * NXP * 2;
    unsigned short* Wihb = (unsigned short*)p;  p += (size_t)1536 * 256 * 2;
    unsigned short* Whhb = (unsigned short*)p;  p += (size_t)1536 * 512 * 2;
    unsigned short* Wthb = (unsigned short*)p;  p += (size_t)256 * 512 * 2;
    unsigned short* Wtxb = (unsigned short*)p;  p += (size_t)256 * 160 * 2;
    if ((size_t)(p - (char*)d_ws) > ws_size) return;

    k_cvt<<<256, 256, 0, stream>>>(Wih, Wihb, 1536 * 256);
    k_cvt<<<256, 256, 0, stream>>>(Whh, Whhb, 1536 * 512);
    k_cvt<<<64, 256, 0, stream>>>(Wth, Wthb, 256 * 512);
    k_cvt<<<32, 256, 0, stream>>>(Wtx, Wtxb, 256 * 160);
    hipMemsetAsync(flags, 0, 32768, stream);
    hipMemsetAsync(hb0, 0, (size_t)NB * NH * 2, stream);

    KParams P;
    P.xl = xl; P.xt = xt_; P.xw = xw; P.xs = xs;
    P.bih = bih; P.bhh = bhh; P.bt = bt;
    P.Wihb = Wihb; P.Whhb = Whhb; P.Wthb = Wthb; P.Wtxb = Wtxb;
    P.hb0 = hb0; P.hb1 = hb1; P.xpb = xpb;
    P.out = (float*)d_out; P.flags = flags;

    void* args[] = { &P };
    if (hipLaunchCooperativeKernel((const void*)k_persist, dim3(256), dim3(256),
                                   args, 0, stream) != hipSuccess) {
        k_persist<<<256, 256, 0, stream>>>(P);
    }
}